// Round 8
// baseline (244.630 us; speedup 1.0000x reference)
//
#include <hip/hip_runtime.h>
#include <math.h>

typedef __attribute__((ext_vector_type(8))) _Float16 half8;
typedef __attribute__((ext_vector_type(4))) _Float16 half4;
typedef __attribute__((ext_vector_type(2))) _Float16 half2;
typedef __attribute__((ext_vector_type(4))) float floatx4;
typedef __attribute__((ext_vector_type(4))) unsigned int uintx4;

#define NB    4
#define CIN   64
#define COUT  128
#define IMH   128
#define IMW   256
#define KTOT  576
#define NPIX  (IMH * IMW)
#define PXT   128
#define NDPB  (PXT * 9)        // 1152 descriptors (px x tap)
#define ROWS  4                // staged rows r-2..r+1 (|new_r - r| < 1.415 proven)
#define CSTW  6                // u32 words per staged col (4 data f16x8 + 2 pad)
#define NCOL  257              // cols 0..255 + zero col 256
#define RSTW  (NCOL * CSTW)    // 1542 u32 words per staged row
#define KCH   96               // padded K per chunk (72 real + 24 zeros)

__device__ __forceinline__ unsigned pkrtz2(float a, float b) {
  unsigned r;
  asm("v_cvt_pkrtz_f16_f32 %0, %1, %2" : "=v"(r) : "v"(a), "v"(b));
  return r;
}
__device__ __forceinline__ half4 bcl(unsigned u) {
  half2 h; __builtin_memcpy(&h, &u, 4);
  return __builtin_shufflevector(h, h, 0, 0, 0, 0);
}
__device__ __forceinline__ half4 bch(unsigned u) {
  half2 h; __builtin_memcpy(&h, &u, 4);
  return __builtin_shufflevector(h, h, 1, 1, 1, 1);
}

// ---- kernel 1: weight fp32 [co][ci*9+t] -> f16, K' = chunk*96 + t*8 + (ci&7) ----
__global__ __launch_bounds__(256) void prep_w_kernel(const float* __restrict__ w,
                                                     unsigned short* __restrict__ wbf) {
  int idx = blockIdx.x * 256 + threadIdx.x;
  if (idx >= COUT * 8 * KCH) return;
  int co = idx / (8 * KCH);
  int K2 = idx - co * (8 * KCH);
  int cb = K2 / KCH, kk = K2 - cb * KCH;
  unsigned short v = 0;
  if (kk < 72) {
    int t = kk >> 3, chl = kk & 7;
    int ci = cb * 8 + chl;
    _Float16 h = (_Float16)w[co * KTOT + ci * 9 + t];
    __builtin_memcpy(&v, &h, 2);
  }
  wbf[(K2 >> 3) * (COUT * 8) + co * 8 + (K2 & 7)] = v;
}

// ---- kernel 2: per-lane register B-fragments, no Sl, 1 barrier/chunk ----
// Each lane (q=lane>>4, p=lane&15) owns B-frag slices (px_base+nt*16+p, tap=4ks+q):
// gathers its own 8-channel sample directly into MFMA B regs. stg double-buffered.
__global__ __launch_bounds__(512, 4) void sphconv_kernel(
    const float* __restrict__ x, const unsigned short* __restrict__ wbf,
    const float* __restrict__ bias, float* __restrict__ out) {
  __shared__ __align__(16) unsigned int stg[2][ROWS * RSTW];  // 2 x 24,672 B
  __shared__ __align__(16) unsigned int descL[NDPB * 4];      // 18,432 B records
  __shared__ double tapA[9];       // atan-term (col-independent)
  __shared__ float  tapWy[9][2];   // wy0m, wy1m
  __shared__ int    tapRo[9][2];   // rt*RSTW, rb*RSTW

  const int tid  = threadIdx.x;
  const int lane = tid & 63;
  const int wv   = tid >> 6;
  // XCD-chunked swizzle (bijective, 256 = 8*32)
  const int lin = blockIdx.x + 2 * blockIdx.y;
  const int sw  = (lin & 7) * 32 + (lin >> 3);
  const int ct  = sw >> 7;
  const int r   = sw & 127;
  const int n   = blockIdx.z;
  const int c0  = ct * PXT;
  const int co_base = (wv & 1) * 64;
  const int px_base = (wv >> 1) * 32;
  const int rlo  = min(max(r - 2, 0), IMH - ROWS);
  const int q    = lane >> 4;       // MFMA K-row group = tap mod 4
  const int p    = lane & 15;       // MFMA col = px offset
  // staging roles: ch-pair x col-group x row-pair
  const int sp  = tid & 3;
  const int scg = (tid >> 2) & 63;
  const int srr = tid >> 8;

  const float* xn = x + (size_t)n * CIN * NPIX;

  // ---- prologue: issue chunk-0 staging loads (land during tap/desc gen) ----
  floatx4 nx[4];
  #pragma unroll
  for (int c = 0; c < 2; c++)
    #pragma unroll
    for (int rw = 0; rw < 2; rw++)
      nx[c * 2 + rw] = *(const floatx4*)(xn + (size_t)(sp * 2 + c) * NPIX
                                         + (size_t)(rlo + srr * 2 + rw) * IMW + scg * 4);

  // ---- phase 0a: per-tap f64 transcendentals (9 designated lanes) ----
  {
    int myk = -1;
    if (lane == 0) myk = wv;
    if (wv == 0 && lane == 32) myk = 8;
    if (myk >= 0) {
      const double pi = 3.14159265358979323846;
      double dphi = pi / IMH;
      double dth  = 2.0 * pi / IMW;
      double t  = tan(dth);
      double pp = tan(dphi);
      double sp_ = pp / cos(dth);
      double phi  = -(((double)r + 0.5) / IMH * pi - pi * 0.5);
      double sphi = sin(phi), cphi = cos(phi);
      int i = myk / 3, j = myk % 3;
      double atv, new_r;
      if (myk == 4) {
        atv = 0.0; new_r = (double)r;
      } else {
        double X = (j == 0) ? -t : ((j == 2) ? t : 0.0);
        double Y = 0.0;
        if (i == 0)      Y = (j == 1) ?  pp :  sp_;
        else if (i == 2) Y = (j == 1) ? -pp : -sp_;
        double rho = sqrt(X * X + Y * Y);
        double v   = atan(rho);
        double sv = sin(v), cv = cos(v);
        double arg = cv * sphi + Y * sv * cphi / rho;
        arg = fmin(1.0, fmax(-1.0, arg));
        double new_phi = asin(arg);
        double denom = rho * cphi * cv - Y * sphi * sv;
        atv = atan(X * sv / denom);
        new_r = (-new_phi + pi * 0.5) * IMH / pi - 0.5;
      }
      float gy = (float)(new_r * 2.0 / IMH - 1.0);
      float iy = ((gy + 1.0f) * (float)IMH - 1.0f) * 0.5f;
      float fy = floorf(iy); int y0 = (int)fy;
      float wy1 = iy - fy, wy0 = 1.0f - wy1;
      int y1 = y0 + 1;
      bool vy0 = (y0 >= 0) & (y0 <= IMH - 1);
      bool vy1 = (y1 >= 0) & (y1 <= IMH - 1);
      int y0c = min(max(y0, 0), IMH - 1), y1c = min(max(y1, 0), IMH - 1);
      int rt = min(max(y0c - rlo, 0), ROWS - 1);
      int rb = min(max(y1c - rlo, 0), ROWS - 1);
      tapA[myk] = atv;
      tapWy[myk][0] = vy0 ? wy0 : 0.0f;
      tapWy[myk][1] = vy1 ? wy1 : 0.0f;
      tapRo[myk][0] = rt * RSTW;
      tapRo[myk][1] = rb * RSTW;
    }
  }
  __syncthreads();   // taps visible

  // ---- phase 0b: per-descriptor x-side -> 16B record in descL ----
  {
    const double pi = 3.14159265358979323846;
    #pragma unroll
    for (int dd = 0; dd < 3; dd++) {
      if (dd < 2 || tid < NDPB - 1024) {
        int d  = tid + dd * 512;
        int px = d & (PXT - 1), k = d >> 7;
        int c  = c0 + px;
        double nc;
        if (k == 4) {
          nc = (double)c;
        } else {
          double theta = ((double)c + 0.5) / IMW * (2.0 * pi) - pi;
          double new_theta = theta + tapA[k];
          nc = (new_theta + pi) * IMW / (2.0 * pi) - 0.5;
          nc = fmod(nc + (double)IMW, (double)IMW);
        }
        float gx = (float)(nc * 2.0 / IMW - 1.0);
        float ix = ((gx + 1.0f) * (float)IMW - 1.0f) * 0.5f;
        float fx = floorf(ix); int x0 = (int)fx;
        float wx1 = ix - fx, wx0 = 1.0f - wx1;
        int x1 = x0 + 1;
        int x0c = max(x0, 0);
        float w_lo = (x0 >= 0) ? wx0 : wx1;
        float w_hi = (x0 >= 0) ? ((x1 <= IMW - 1) ? wx1 : 0.0f) : 0.0f;
        float wy0m = tapWy[k][0], wy1m = tapWy[k][1];
        int sh0 = ((x0c >> 4) & 1) * 2;
        int sh1 = (((x0c + 1) >> 4) & 1) * 2;
        int dc  = CSTW + sh1 - sh0;
        int offt = tapRo[k][0] + x0c * CSTW + sh0;   // <= 6158, fits 16b
        int offb = tapRo[k][1] + x0c * CSTW + sh0;
        uintx4 rec;
        rec.x = (unsigned)(offt | (offb << 16));
        rec.y = pkrtz2(wy0m * w_lo, wy0m * w_hi);    // (w0, w1)
        rec.z = pkrtz2(wy1m * w_lo, wy1m * w_hi);    // (w2, w3)
        rec.w = (unsigned)dc;
        *(uintx4*)&descL[(px * 9 + k) * 4] = rec;
      }
    }
  }

  // ---- write chunk-0 stage; zero col-256 of BOTH buffers ----
  #pragma unroll
  for (int rw = 0; rw < 2; rw++)
    #pragma unroll
    for (int i = 0; i < 4; i++) {
      int col = scg * 4 + i;
      int sh = ((col >> 4) & 1) * 2;
      stg[0][(srr * 2 + rw) * RSTW + col * CSTW + sh + sp] =
          pkrtz2(nx[rw][i], nx[2 + rw][i]);
    }
  if (tid < 32) stg[tid >> 4][((tid >> 2) & 3) * RSTW + 256 * CSTW + (tid & 3)] = 0u;

  __syncthreads();   // descL + stg[0] ready

  // ---- load this lane's 6 descriptor records (chunk-invariant) ----
  uintx4 R[6];
  #pragma unroll
  for (int nt = 0; nt < 2; nt++)
    #pragma unroll
    for (int j = 0; j < 3; j++) {
      int tap = q + j * 4;
      int px  = px_base + nt * 16 + p;
      if (tap < 9) R[nt * 3 + j] = *(const uintx4*)&descL[(px * 9 + tap) * 4];
      else         R[nt * 3 + j] = (uintx4){0u, 0u, 0u, (unsigned)CSTW};  // zero-weight pad
    }

  floatx4 acc[4][2];
  #pragma unroll
  for (int mt = 0; mt < 4; mt++)
    #pragma unroll
    for (int nt = 0; nt < 2; nt++)
      acc[mt][nt] = (floatx4){0.f, 0.f, 0.f, 0.f};

  #pragma unroll 1
  for (int cb = 0; cb < 8; cb++) {
    // ---- issue next chunk's global loads (land during gather+MFMA) ----
    if (cb < 7) {
      #pragma unroll
      for (int c = 0; c < 2; c++)
        #pragma unroll
        for (int rw = 0; rw < 2; rw++)
          nx[c * 2 + rw] = *(const floatx4*)(xn + (size_t)((cb + 1) * 8 + sp * 2 + c) * NPIX
                                             + (size_t)(rlo + srr * 2 + rw) * IMW + scg * 4);
    }
    // ---- per-lane gather -> B-frag regs -> MFMA (no Sl, wave-local) ----
    const unsigned int* sb = &stg[cb & 1][0];
    #pragma unroll
    for (int nt = 0; nt < 2; nt++) {
      #pragma unroll
      for (int ks = 0; ks < 3; ks++) {
        uintx4 rec = R[nt * 3 + ks];
        unsigned op = rec.x;
        int dc = (int)rec.w;
        const unsigned int* pt = sb + (op & 0xFFFFu);
        const unsigned int* pb = sb + (op >> 16);
        half4 t0  = *(const half4*)(pt);
        half4 t0h = *(const half4*)(pt + 2);
        half4 t1  = *(const half4*)(pt + dc);
        half4 t1h = *(const half4*)(pt + dc + 2);
        half4 b0  = *(const half4*)(pb);
        half4 b0h = *(const half4*)(pb + 2);
        half4 b1  = *(const half4*)(pb + dc);
        half4 b1h = *(const half4*)(pb + dc + 2);
        half4 W0 = bcl(rec.y), W1 = bch(rec.y);
        half4 W2 = bcl(rec.z), W3 = bch(rec.z);
        half4 slo = t0 * W0 + t1 * W1 + b0 * W2 + b1 * W3;   // ch 0-3
        half4 shi = t0h * W0 + t1h * W1 + b0h * W2 + b1h * W3; // ch 4-7
        half8 b = __builtin_shufflevector(slo, shi, 0, 1, 2, 3, 4, 5, 6, 7);
        const unsigned short* arow =
            wbf + (size_t)((cb * 12 + ks * 4 + q) * COUT + co_base + p) * 8;
        __builtin_amdgcn_s_setprio(1);
        #pragma unroll
        for (int mt = 0; mt < 4; mt++) {
          half8 a = *(const half8*)(arow + mt * 16 * 8);
          acc[mt][nt] = __builtin_amdgcn_mfma_f32_16x16x32_f16(a, b, acc[mt][nt], 0, 0, 0);
        }
        __builtin_amdgcn_s_setprio(0);
      }
    }
    // ---- write next chunk's stage into the other buffer ----
    if (cb < 7) {
      #pragma unroll
      for (int rw = 0; rw < 2; rw++)
        #pragma unroll
        for (int i = 0; i < 4; i++) {
          int col = scg * 4 + i;
          int sh = ((col >> 4) & 1) * 2;
          stg[(cb + 1) & 1][(srr * 2 + rw) * RSTW + col * CSTW + sh + sp] =
              pkrtz2(nx[rw][i], nx[2 + rw][i]);
        }
    }
    __syncthreads();   // single barrier: stg[(cb+1)&1] ready, gathers of cb done
  }

  // ---- epilogue: D row = co, col = px ----
  #pragma unroll
  for (int mt = 0; mt < 4; mt++)
    #pragma unroll
    for (int nt = 0; nt < 2; nt++)
      #pragma unroll
      for (int rg = 0; rg < 4; rg++) {
        const int co = co_base + mt * 16 + q * 4 + rg;
        const int cc = c0 + px_base + nt * 16 + p;
        out[(((size_t)n * COUT + co) * IMH + r) * IMW + cc] = acc[mt][nt][rg] + bias[co];
      }
}

extern "C" void kernel_launch(void* const* d_in, const int* in_sizes, int n_in,
                              void* d_out, int out_size, void* d_ws, size_t ws_size,
                              hipStream_t stream) {
  const float* x    = (const float*)d_in[0];
  const float* w    = (const float*)d_in[1];
  const float* bias = (const float*)d_in[2];
  float* out = (float*)d_out;
  unsigned short* wbf = (unsigned short*)d_ws;   // 192 KB workspace
  (void)in_sizes; (void)n_in; (void)out_size; (void)ws_size;

  hipLaunchKernelGGL(prep_w_kernel, dim3((COUT * 8 * KCH + 255) / 256), dim3(256), 0, stream, w, wbf);
  hipLaunchKernelGGL(sphconv_kernel, dim3(IMW / PXT, IMH, NB), dim3(512), 0, stream,
                     x, wbf, bias, out);
}

// Round 9
// 170.655 us; speedup vs baseline: 1.4335x; 1.4335x over previous
//
#include <hip/hip_runtime.h>
#include <math.h>

typedef __attribute__((ext_vector_type(8))) _Float16 half8;
typedef __attribute__((ext_vector_type(4))) _Float16 half4;
typedef __attribute__((ext_vector_type(2))) _Float16 half2;
typedef __attribute__((ext_vector_type(4))) float floatx4;
typedef __attribute__((ext_vector_type(4))) unsigned int uintx4;

#define NB    4
#define CIN   64
#define COUT  128
#define IMH   128
#define IMW   256
#define KTOT  576
#define NPIX  (IMH * IMW)
#define PXT   128
#define NDPB  (PXT * 9)        // 1152 real descriptors (px x tap)
#define ROWS  4                // staged rows r-2..r+1 (|new_r - r| < 1.415 proven)
#define CSTW  6                // u32 words per staged col (4 data f16x8 + 2 pad)
#define NCOL  257              // cols 0..255 + zero col 256
#define RSTW  (NCOL * CSTW)    // 1542 u32 words per staged row
#define KCH   96               // padded K per chunk (72 real + 24 zeros)

__device__ __forceinline__ unsigned pkrtz2(float a, float b) {
  unsigned r;
  asm("v_cvt_pkrtz_f16_f32 %0, %1, %2" : "=v"(r) : "v"(a), "v"(b));
  return r;
}
__device__ __forceinline__ half4 bcl(unsigned u) {
  half2 h; __builtin_memcpy(&h, &u, 4);
  return __builtin_shufflevector(h, h, 0, 0, 0, 0);
}
__device__ __forceinline__ half4 bch(unsigned u) {
  half2 h; __builtin_memcpy(&h, &u, 4);
  return __builtin_shufflevector(h, h, 1, 1, 1, 1);
}

// ---- kernel 1: weight fp32 [co][ci*9+t] -> f16, K' = chunk*96 + t*8 + (ci&7) ----
__global__ __launch_bounds__(256) void prep_w_kernel(const float* __restrict__ w,
                                                     unsigned short* __restrict__ wbf) {
  int idx = blockIdx.x * 256 + threadIdx.x;
  if (idx >= COUT * 8 * KCH) return;
  int co = idx / (8 * KCH);
  int K2 = idx - co * (8 * KCH);
  int cb = K2 / KCH, kk = K2 - cb * KCH;
  unsigned short v = 0;
  if (kk < 72) {
    int t = kk >> 3, chl = kk & 7;
    int ci = cb * 8 + chl;
    _Float16 h = (_Float16)w[co * KTOT + ci * 9 + t];
    __builtin_memcpy(&v, &h, 2);
  }
  wbf[(K2 >> 3) * (COUT * 8) + co * 8 + (K2 & 7)] = v;
}

// ---- kernel 2: per-lane register B-fragments, descL re-read per chunk ----
// Each lane (q=lane>>4, p=lane&15) owns B-frag slices (px_base+nt*16+p, tap=4ks+q);
// descriptor records live in LDS [tap][px] (NOT register-cached - R8 spilled).
__global__ __launch_bounds__(512, 4) void sphconv_kernel(
    const float* __restrict__ x, const unsigned short* __restrict__ wbf,
    const float* __restrict__ bias, float* __restrict__ out) {
  __shared__ __align__(16) unsigned int stg[2][ROWS * RSTW];  // 2 x 24,672 B
  __shared__ __align__(16) unsigned int descL[12 * PXT * 4];  // 24,576 B [tap][px]
  __shared__ double tapA[9];       // atan-term (col-independent)
  __shared__ float  tapWy[9][2];   // wy0m, wy1m
  __shared__ int    tapRo[9][2];   // rt*RSTW, rb*RSTW

  const int tid  = threadIdx.x;
  const int lane = tid & 63;
  const int wv   = tid >> 6;
  // XCD-chunked swizzle (bijective, 256 = 8*32)
  const int lin = blockIdx.x + 2 * blockIdx.y;
  const int sw  = (lin & 7) * 32 + (lin >> 3);
  const int ct  = sw >> 7;
  const int r   = sw & 127;
  const int n   = blockIdx.z;
  const int c0  = ct * PXT;
  const int co_base = (wv & 1) * 64;
  const int px_base = (wv >> 1) * 32;
  const int rlo  = min(max(r - 2, 0), IMH - ROWS);
  const int q    = lane >> 4;       // MFMA K-row group = tap mod 4
  const int p    = lane & 15;       // MFMA col = px offset
  // staging roles: ch-pair x col-group x row-pair
  const int sp  = tid & 3;
  const int scg = (tid >> 2) & 63;
  const int srr = tid >> 8;

  const float* xn = x + (size_t)n * CIN * NPIX;

  // ---- prologue: issue chunk-0 staging loads (land during tap/desc gen) ----
  floatx4 nx[4];
  #pragma unroll
  for (int c = 0; c < 2; c++)
    #pragma unroll
    for (int rw = 0; rw < 2; rw++)
      nx[c * 2 + rw] = *(const floatx4*)(xn + (size_t)(sp * 2 + c) * NPIX
                                         + (size_t)(rlo + srr * 2 + rw) * IMW + scg * 4);

  // ---- phase 0a: per-tap f64 transcendentals (9 designated lanes) ----
  {
    int myk = -1;
    if (lane == 0) myk = wv;
    if (wv == 0 && lane == 32) myk = 8;
    if (myk >= 0) {
      const double pi = 3.14159265358979323846;
      double dphi = pi / IMH;
      double dth  = 2.0 * pi / IMW;
      double t  = tan(dth);
      double pp = tan(dphi);
      double sp_ = pp / cos(dth);
      double phi  = -(((double)r + 0.5) / IMH * pi - pi * 0.5);
      double sphi = sin(phi), cphi = cos(phi);
      int i = myk / 3, j = myk % 3;
      double atv, new_r;
      if (myk == 4) {
        atv = 0.0; new_r = (double)r;
      } else {
        double X = (j == 0) ? -t : ((j == 2) ? t : 0.0);
        double Y = 0.0;
        if (i == 0)      Y = (j == 1) ?  pp :  sp_;
        else if (i == 2) Y = (j == 1) ? -pp : -sp_;
        double rho = sqrt(X * X + Y * Y);
        double v   = atan(rho);
        double sv = sin(v), cv = cos(v);
        double arg = cv * sphi + Y * sv * cphi / rho;
        arg = fmin(1.0, fmax(-1.0, arg));
        double new_phi = asin(arg);
        double denom = rho * cphi * cv - Y * sphi * sv;
        atv = atan(X * sv / denom);
        new_r = (-new_phi + pi * 0.5) * IMH / pi - 0.5;
      }
      float gy = (float)(new_r * 2.0 / IMH - 1.0);
      float iy = ((gy + 1.0f) * (float)IMH - 1.0f) * 0.5f;
      float fy = floorf(iy); int y0 = (int)fy;
      float wy1 = iy - fy, wy0 = 1.0f - wy1;
      int y1 = y0 + 1;
      bool vy0 = (y0 >= 0) & (y0 <= IMH - 1);
      bool vy1 = (y1 >= 0) & (y1 <= IMH - 1);
      int y0c = min(max(y0, 0), IMH - 1), y1c = min(max(y1, 0), IMH - 1);
      int rt = min(max(y0c - rlo, 0), ROWS - 1);
      int rb = min(max(y1c - rlo, 0), ROWS - 1);
      tapA[myk] = atv;
      tapWy[myk][0] = vy0 ? wy0 : 0.0f;
      tapWy[myk][1] = vy1 ? wy1 : 0.0f;
      tapRo[myk][0] = rt * RSTW;
      tapRo[myk][1] = rb * RSTW;
    }
  }
  __syncthreads();   // taps visible

  // ---- phase 0b: per-descriptor x-side -> 16B record in descL[tap][px] ----
  {
    const double pi = 3.14159265358979323846;
    #pragma unroll
    for (int dd = 0; dd < 3; dd++) {
      if (dd < 2 || tid < NDPB - 1024) {
        int d  = tid + dd * 512;
        int px = d & (PXT - 1), k = d >> 7;
        int c  = c0 + px;
        double nc;
        if (k == 4) {
          nc = (double)c;
        } else {
          double theta = ((double)c + 0.5) / IMW * (2.0 * pi) - pi;
          double new_theta = theta + tapA[k];
          nc = (new_theta + pi) * IMW / (2.0 * pi) - 0.5;
          nc = fmod(nc + (double)IMW, (double)IMW);
        }
        float gx = (float)(nc * 2.0 / IMW - 1.0);
        float ix = ((gx + 1.0f) * (float)IMW - 1.0f) * 0.5f;
        float fx = floorf(ix); int x0 = (int)fx;
        float wx1 = ix - fx, wx0 = 1.0f - wx1;
        int x1 = x0 + 1;
        int x0c = max(x0, 0);
        float w_lo = (x0 >= 0) ? wx0 : wx1;
        float w_hi = (x0 >= 0) ? ((x1 <= IMW - 1) ? wx1 : 0.0f) : 0.0f;
        float wy0m = tapWy[k][0], wy1m = tapWy[k][1];
        int sh0 = ((x0c >> 4) & 1) * 2;
        int sh1 = (((x0c + 1) >> 4) & 1) * 2;
        int dc  = CSTW + sh1 - sh0;
        int offt = tapRo[k][0] + x0c * CSTW + sh0;   // <= 6158, fits 16b
        int offb = tapRo[k][1] + x0c * CSTW + sh0;
        uintx4 rec;
        rec.x = (unsigned)(offt | (offb << 16));
        rec.y = pkrtz2(wy0m * w_lo, wy0m * w_hi);    // (w0, w1)
        rec.z = pkrtz2(wy1m * w_lo, wy1m * w_hi);    // (w2, w3)
        rec.w = (unsigned)dc;
        *(uintx4*)&descL[(k * PXT + px) * 4] = rec;
      }
    }
  }
  // zero-weight pad records for taps 9..11 (op=0 -> valid addr, weight 0)
  if (tid < 3 * PXT) {
    uintx4 zr = {0u, 0u, 0u, (unsigned)CSTW};
    *(uintx4*)&descL[((9 + (tid >> 7)) * PXT + (tid & (PXT - 1))) * 4] = zr;
  }

  // ---- write chunk-0 stage; zero col-256 of BOTH buffers ----
  #pragma unroll
  for (int rw = 0; rw < 2; rw++)
    #pragma unroll
    for (int i = 0; i < 4; i++) {
      int col = scg * 4 + i;
      int sh = ((col >> 4) & 1) * 2;
      stg[0][(srr * 2 + rw) * RSTW + col * CSTW + sh + sp] =
          pkrtz2(nx[rw][i], nx[2 + rw][i]);
    }
  if (tid < 32) stg[tid >> 4][((tid >> 2) & 3) * RSTW + 256 * CSTW + (tid & 3)] = 0u;

  floatx4 acc[4][2];
  #pragma unroll
  for (int mt = 0; mt < 4; mt++)
    #pragma unroll
    for (int nt = 0; nt < 2; nt++)
      acc[mt][nt] = (floatx4){0.f, 0.f, 0.f, 0.f};

  __syncthreads();   // descL + stg[0] ready

  #pragma unroll 1
  for (int cb = 0; cb < 8; cb++) {
    // ---- issue next chunk's global loads (land during gather+MFMA) ----
    if (cb < 7) {
      #pragma unroll
      for (int c = 0; c < 2; c++)
        #pragma unroll
        for (int rw = 0; rw < 2; rw++)
          nx[c * 2 + rw] = *(const floatx4*)(xn + (size_t)((cb + 1) * 8 + sp * 2 + c) * NPIX
                                             + (size_t)(rlo + srr * 2 + rw) * IMW + scg * 4);
    }
    // ---- per-lane gather -> B-frag regs -> MFMA (desc re-read from LDS) ----
    const unsigned int* sb = &stg[cb & 1][0];
    #pragma unroll
    for (int nt = 0; nt < 2; nt++) {
      const int pxl = px_base + nt * 16 + p;
      #pragma unroll
      for (int ks = 0; ks < 3; ks++) {
        uintx4 rec = *(const uintx4*)&descL[((ks * 4 + q) * PXT + pxl) * 4];
        unsigned op = rec.x;
        int dc = (int)rec.w;
        const unsigned int* pt = sb + (op & 0xFFFFu);
        const unsigned int* pb = sb + (op >> 16);
        half4 t0  = *(const half4*)(pt);
        half4 t0h = *(const half4*)(pt + 2);
        half4 t1  = *(const half4*)(pt + dc);
        half4 t1h = *(const half4*)(pt + dc + 2);
        half4 b0  = *(const half4*)(pb);
        half4 b0h = *(const half4*)(pb + 2);
        half4 b1  = *(const half4*)(pb + dc);
        half4 b1h = *(const half4*)(pb + dc + 2);
        half4 W0 = bcl(rec.y), W1 = bch(rec.y);
        half4 W2 = bcl(rec.z), W3 = bch(rec.z);
        half4 slo = t0 * W0 + t1 * W1 + b0 * W2 + b1 * W3;     // ch 0-3
        half4 shi = t0h * W0 + t1h * W1 + b0h * W2 + b1h * W3; // ch 4-7
        half8 b = __builtin_shufflevector(slo, shi, 0, 1, 2, 3, 4, 5, 6, 7);
        const unsigned short* arow =
            wbf + (size_t)((cb * 12 + ks * 4 + q) * COUT + co_base + p) * 8;
        __builtin_amdgcn_s_setprio(1);
        #pragma unroll
        for (int mt = 0; mt < 4; mt++) {
          half8 a = *(const half8*)(arow + mt * 16 * 8);
          acc[mt][nt] = __builtin_amdgcn_mfma_f32_16x16x32_f16(a, b, acc[mt][nt], 0, 0, 0);
        }
        __builtin_amdgcn_s_setprio(0);
      }
    }
    // ---- write next chunk's stage into the other buffer ----
    if (cb < 7) {
      #pragma unroll
      for (int rw = 0; rw < 2; rw++)
        #pragma unroll
        for (int i = 0; i < 4; i++) {
          int col = scg * 4 + i;
          int sh = ((col >> 4) & 1) * 2;
          stg[(cb + 1) & 1][(srr * 2 + rw) * RSTW + col * CSTW + sh + sp] =
              pkrtz2(nx[rw][i], nx[2 + rw][i]);
        }
    }
    __syncthreads();   // single barrier: stg[(cb+1)&1] ready, gathers of cb done
  }

  // ---- epilogue: D row = co, col = px ----
  #pragma unroll
  for (int mt = 0; mt < 4; mt++)
    #pragma unroll
    for (int nt = 0; nt < 2; nt++)
      #pragma unroll
      for (int rg = 0; rg < 4; rg++) {
        const int co = co_base + mt * 16 + q * 4 + rg;
        const int cc = c0 + px_base + nt * 16 + p;
        out[(((size_t)n * COUT + co) * IMH + r) * IMW + cc] = acc[mt][nt][rg] + bias[co];
      }
}

extern "C" void kernel_launch(void* const* d_in, const int* in_sizes, int n_in,
                              void* d_out, int out_size, void* d_ws, size_t ws_size,
                              hipStream_t stream) {
  const float* x    = (const float*)d_in[0];
  const float* w    = (const float*)d_in[1];
  const float* bias = (const float*)d_in[2];
  float* out = (float*)d_out;
  unsigned short* wbf = (unsigned short*)d_ws;   // 192 KB workspace
  (void)in_sizes; (void)n_in; (void)out_size; (void)ws_size;

  hipLaunchKernelGGL(prep_w_kernel, dim3((COUT * 8 * KCH + 255) / 256), dim3(256), 0, stream, w, wbf);
  hipLaunchKernelGGL(sphconv_kernel, dim3(IMW / PXT, IMH, NB), dim3(512), 0, stream,
                     x, wbf, bias, out);
}

// Round 12
// 164.171 us; speedup vs baseline: 1.4901x; 1.0395x over previous
//
#include <hip/hip_runtime.h>
#include <math.h>

typedef __attribute__((ext_vector_type(8))) _Float16 half8;
typedef __attribute__((ext_vector_type(4))) _Float16 half4;
typedef __attribute__((ext_vector_type(2))) _Float16 half2;
typedef __attribute__((ext_vector_type(4))) float floatx4;
typedef __attribute__((ext_vector_type(4))) unsigned int uintx4;

#define NB    4
#define CIN   64
#define COUT  128
#define IMH   128
#define IMW   256
#define KTOT  576
#define NPIX  (IMH * IMW)
#define PXT   128
#define NDPB  (PXT * 9)        // 1152 real descriptors (px x tap)
#define ROWS  4                // staged rows r-2..r+1 (|new_r - r| < 1.415 proven)
#define KCH   96               // padded K per chunk (72 real + 24 zeros)
#define DSTR  520              // descL per-tap stride, u32 words (128*4 + 8 bank skew)
#define XT_OFF 262144          // x_t byte offset in workspace (after 192KB wbf)
#define XT_BYTES ((size_t)NB * 8 * IMH * IMW * 16)

__device__ __forceinline__ unsigned pkrtz2(float a, float b) {
  unsigned r;
  asm("v_cvt_pkrtz_f16_f32 %0, %1, %2" : "=v"(r) : "v"(a), "v"(b));
  return r;
}
__device__ __forceinline__ half4 bcl(unsigned u) {
  half2 h; __builtin_memcpy(&h, &u, 4);
  return __builtin_shufflevector(h, h, 0, 0, 0, 0);
}
__device__ __forceinline__ half4 bch(unsigned u) {
  half2 h; __builtin_memcpy(&h, &u, 4);
  return __builtin_shufflevector(h, h, 1, 1, 1, 1);
}
__device__ __forceinline__ half8 bcl8(unsigned u) {
  half2 h; __builtin_memcpy(&h, &u, 4);
  return __builtin_shufflevector(h, h, 0, 0, 0, 0, 0, 0, 0, 0);
}
__device__ __forceinline__ half8 bch8(unsigned u) {
  half2 h; __builtin_memcpy(&h, &u, 4);
  return __builtin_shufflevector(h, h, 1, 1, 1, 1, 1, 1, 1, 1);
}
__device__ __forceinline__ void gload_lds16(const void* g, void* l) {
  __builtin_amdgcn_global_load_lds(
      (const __attribute__((address_space(1))) unsigned int*)g,
      (__attribute__((address_space(3))) unsigned int*)l, 16, 0, 0);
}

// ---- kernel 1: weight fp32 [co][ci*9+t] -> f16, K' = chunk*96 + t*8 + (ci&7) ----
__global__ __launch_bounds__(256) void prep_w_kernel(const float* __restrict__ w,
                                                     unsigned short* __restrict__ wbf) {
  int idx = blockIdx.x * 256 + threadIdx.x;
  if (idx >= COUT * 8 * KCH) return;
  int co = idx / (8 * KCH);
  int K2 = idx - co * (8 * KCH);
  int cb = K2 / KCH, kk = K2 - cb * KCH;
  unsigned short v = 0;
  if (kk < 72) {
    int t = kk >> 3, chl = kk & 7;
    int ci = cb * 8 + chl;
    _Float16 h = (_Float16)w[co * KTOT + ci * 9 + t];
    __builtin_memcpy(&v, &h, 2);
  }
  wbf[(K2 >> 3) * (COUT * 8) + co * 8 + (K2 & 7)] = v;
}

// ---- kernel 1b: x NCHW f32 -> x_t[n][cb][r][c][8ch] f16 (16B gather units) ----
__global__ __launch_bounds__(256) void prep_x_kernel(const float* __restrict__ x,
                                                     unsigned short* __restrict__ xt) {
  int idx = blockIdx.x * 256 + threadIdx.x;   // (n*8+cb)*32768 + r*256 + c
  int c   = idx & 255;
  int rr  = (idx >> 8) & 127;
  int ncb = idx >> 15;
  int n = ncb >> 3, cb = ncb & 7;
  const float* src = x + (size_t)(n * CIN + cb * 8) * NPIX + rr * IMW + c;
  unsigned o4[4];
  #pragma unroll
  for (int j = 0; j < 4; j++)
    o4[j] = pkrtz2(src[(size_t)(2 * j) * NPIX], src[(size_t)(2 * j + 1) * NPIX]);
  *(uintx4*)(xt + (size_t)idx * 8) = *(uintx4*)o4;
}

// ================= FAST PATH: x_t gather, global_load_lds staging ===============
// stg[buf] = [4 rows][256 cols][8ch f16] linear 16KB; per rec: 1 rec b128 + 4 b128.
__global__ __launch_bounds__(512, 4) void sphconv_fast(
    const unsigned short* __restrict__ xt, const unsigned short* __restrict__ wbf,
    const float* __restrict__ bias, float* __restrict__ out) {
  __shared__ __align__(16) unsigned int stg[2][ROWS * IMW * 4];  // 2 x 16,384 B
  __shared__ __align__(16) unsigned int descL[12 * DSTR];        // 24,960 B skewed
  __shared__ double tapA[9];
  __shared__ float  tapWy[9][2];
  __shared__ int    tapRo[9][2];   // rt*1024, rb*1024 (word units)

  const int tid  = threadIdx.x;
  const int lane = tid & 63;
  const int wv   = tid >> 6;
  const int lin = blockIdx.x + 2 * blockIdx.y;
  const int sw  = (lin & 7) * 32 + (lin >> 3);
  const int ct  = sw >> 7;
  const int r   = sw & 127;
  const int n   = blockIdx.z;
  const int c0  = ct * PXT;
  const int co_base = (wv & 1) * 64;
  const int px_base = (wv >> 1) * 32;
  const int rlo  = min(max(r - 2, 0), IMH - ROWS);
  const int q    = lane >> 4;
  const int p    = lane & 15;

  // ---- issue chunk-0 staging immediately (lands during f64 desc-gen) ----
  {
    const char* gs = (const char*)xt
        + ((size_t)((n * 8 + 0) * IMH + rlo) * IMW) * 16 + wv * 1024 + lane * 16;
    char* lb = (char*)&stg[0][0] + wv * 1024;
    gload_lds16(gs, lb);
    gload_lds16(gs + 8192, lb + 8192);
  }

  // ---- phase 0a: per-tap f64 transcendentals (9 designated lanes) ----
  {
    int myk = -1;
    if (lane == 0) myk = wv;
    if (wv == 0 && lane == 32) myk = 8;
    if (myk >= 0) {
      const double pi = 3.14159265358979323846;
      double dphi = pi / IMH;
      double dth  = 2.0 * pi / IMW;
      double t  = tan(dth);
      double pp = tan(dphi);
      double sp_ = pp / cos(dth);
      double phi  = -(((double)r + 0.5) / IMH * pi - pi * 0.5);
      double sphi = sin(phi), cphi = cos(phi);
      int i = myk / 3, j = myk % 3;
      double atv, new_r;
      if (myk == 4) {
        atv = 0.0; new_r = (double)r;
      } else {
        double X = (j == 0) ? -t : ((j == 2) ? t : 0.0);
        double Y = 0.0;
        if (i == 0)      Y = (j == 1) ?  pp :  sp_;
        else if (i == 2) Y = (j == 1) ? -pp : -sp_;
        double rho = sqrt(X * X + Y * Y);
        double v   = atan(rho);
        double sv = sin(v), cv = cos(v);
        double arg = cv * sphi + Y * sv * cphi / rho;
        arg = fmin(1.0, fmax(-1.0, arg));
        double new_phi = asin(arg);
        double denom = rho * cphi * cv - Y * sphi * sv;
        atv = atan(X * sv / denom);
        new_r = (-new_phi + pi * 0.5) * IMH / pi - 0.5;
      }
      float gy = (float)(new_r * 2.0 / IMH - 1.0);
      float iy = ((gy + 1.0f) * (float)IMH - 1.0f) * 0.5f;
      float fy = floorf(iy); int y0 = (int)fy;
      float wy1 = iy - fy, wy0 = 1.0f - wy1;
      int y1 = y0 + 1;
      bool vy0 = (y0 >= 0) & (y0 <= IMH - 1);
      bool vy1 = (y1 >= 0) & (y1 <= IMH - 1);
      int y0c = min(max(y0, 0), IMH - 1), y1c = min(max(y1, 0), IMH - 1);
      int rt = min(max(y0c - rlo, 0), ROWS - 1);
      int rb = min(max(y1c - rlo, 0), ROWS - 1);
      tapA[myk] = atv;
      tapWy[myk][0] = vy0 ? wy0 : 0.0f;
      tapWy[myk][1] = vy1 ? wy1 : 0.0f;
      tapRo[myk][0] = rt * (IMW * 4);
      tapRo[myk][1] = rb * (IMW * 4);
    }
  }
  __syncthreads();

  // ---- phase 0b: per-descriptor x-side -> 16B record in descL[tap][px] ----
  {
    const double pi = 3.14159265358979323846;
    #pragma unroll
    for (int dd = 0; dd < 3; dd++) {
      if (dd < 2 || tid < NDPB - 1024) {
        int d  = tid + dd * 512;
        int px = d & (PXT - 1), k = d >> 7;
        int c  = c0 + px;
        double nc;
        if (k == 4) {
          nc = (double)c;
        } else {
          double theta = ((double)c + 0.5) / IMW * (2.0 * pi) - pi;
          double new_theta = theta + tapA[k];
          nc = (new_theta + pi) * IMW / (2.0 * pi) - 0.5;
          nc = fmod(nc + (double)IMW, (double)IMW);
        }
        float gx = (float)(nc * 2.0 / IMW - 1.0);
        float ix = ((gx + 1.0f) * (float)IMW - 1.0f) * 0.5f;
        float fx = floorf(ix); int x0 = (int)fx;
        float wx1 = ix - fx, wx0 = 1.0f - wx1;
        int x1 = x0 + 1;
        int x0c = max(x0, 0);
        float w_lo = (x0 >= 0) ? wx0 : wx1;
        float w_hi = (x0 >= 0) ? ((x1 <= IMW - 1) ? wx1 : 0.0f) : 0.0f;
        float wy0m = tapWy[k][0], wy1m = tapWy[k][1];
        int dc = (x1 <= IMW - 1) ? 4 : 0;            // hi-col offset (words); OOB reads lo col w/ weight 0
        int offt = tapRo[k][0] + x0c * 4;            // <= 4092, fits 16b; +dc+3 <= 4095
        int offb = tapRo[k][1] + x0c * 4;
        uintx4 rec;
        rec.x = (unsigned)(offt | (offb << 16));
        rec.y = pkrtz2(wy0m * w_lo, wy0m * w_hi);
        rec.z = pkrtz2(wy1m * w_lo, wy1m * w_hi);
        rec.w = (unsigned)dc;
        *(uintx4*)&descL[k * DSTR + px * 4] = rec;
      }
    }
  }
  // zero-weight pad records for taps 9..11
  if (tid < 3 * PXT) {
    uintx4 zr = {0u, 0u, 0u, 0u};
    *(uintx4*)&descL[(9 + (tid >> 7)) * DSTR + (tid & (PXT - 1)) * 4] = zr;
  }

  floatx4 acc[4][2];
  #pragma unroll
  for (int mt = 0; mt < 4; mt++)
    #pragma unroll
    for (int nt = 0; nt < 2; nt++)
      acc[mt][nt] = (floatx4){0.f, 0.f, 0.f, 0.f};

  __syncthreads();   // descL + stg[0] (vmcnt drained by compiler) ready

  #pragma unroll 1
  for (int cb = 0; cb < 8; cb++) {
    // ---- issue next chunk's staging (async, lands under gather+MFMA) ----
    if (cb < 7) {
      const char* gs = (const char*)xt
          + ((size_t)((n * 8 + cb + 1) * IMH + rlo) * IMW) * 16 + wv * 1024 + lane * 16;
      char* lb = (char*)&stg[(cb + 1) & 1][0] + wv * 1024;
      gload_lds16(gs, lb);
      gload_lds16(gs + 8192, lb + 8192);
    }
    // ---- per-lane gather (4 aligned b128 / rec) -> B-frag -> MFMA ----
    const unsigned int* sb = &stg[cb & 1][0];
    #pragma unroll
    for (int nt = 0; nt < 2; nt++) {
      const int pxl = px_base + nt * 16 + p;
      #pragma unroll
      for (int ks = 0; ks < 3; ks++) {
        uintx4 rec = *(const uintx4*)&descL[(ks * 4 + q) * DSTR + pxl * 4];
        unsigned op = rec.x;
        int dc = (int)rec.w;
        const unsigned int* pt = sb + (op & 0xFFFFu);
        const unsigned int* pb = sb + (op >> 16);
        half8 t0 = *(const half8*)pt;
        half8 t1 = *(const half8*)(pt + dc);
        half8 b0 = *(const half8*)pb;
        half8 b1 = *(const half8*)(pb + dc);
        half8 W0 = bcl8(rec.y), W1 = bch8(rec.y);
        half8 W2 = bcl8(rec.z), W3 = bch8(rec.z);
        half8 b = t0 * W0 + t1 * W1 + b0 * W2 + b1 * W3;   // all 8 ch at once
        const unsigned short* arow =
            wbf + (size_t)((cb * 12 + ks * 4 + q) * COUT + co_base + p) * 8;
        __builtin_amdgcn_s_setprio(1);
        #pragma unroll
        for (int mt = 0; mt < 4; mt++) {
          half8 a = *(const half8*)(arow + mt * 16 * 8);
          acc[mt][nt] = __builtin_amdgcn_mfma_f32_16x16x32_f16(a, b, acc[mt][nt], 0, 0, 0);
        }
        __builtin_amdgcn_s_setprio(0);
      }
    }
    __syncthreads();   // drains gload_lds (vmcnt) + orders buffer reuse
  }

  #pragma unroll
  for (int mt = 0; mt < 4; mt++)
    #pragma unroll
    for (int nt = 0; nt < 2; nt++)
      #pragma unroll
      for (int rg = 0; rg < 4; rg++) {
        const int co = co_base + mt * 16 + q * 4 + rg;
        const int cc = c0 + px_base + nt * 16 + p;
        out[(((size_t)n * COUT + co) * IMH + r) * IMW + cc] = acc[mt][nt][rg] + bias[co];
      }
}

// ================= FALLBACK (R9, measured 105us): ws too small for x_t ==========
#define F_CSTW  6
#define F_NCOL  257
#define F_RSTW  (F_NCOL * F_CSTW)
__global__ __launch_bounds__(512, 4) void sphconv_fb(
    const float* __restrict__ x, const unsigned short* __restrict__ wbf,
    const float* __restrict__ bias, float* __restrict__ out) {
  __shared__ __align__(16) unsigned int stg[2][ROWS * F_RSTW];
  __shared__ __align__(16) unsigned int descL[12 * PXT * 4];
  __shared__ double tapA[9];
  __shared__ float  tapWy[9][2];
  __shared__ int    tapRo[9][2];

  const int tid  = threadIdx.x;
  const int lane = tid & 63;
  const int wv   = tid >> 6;
  const int lin = blockIdx.x + 2 * blockIdx.y;
  const int sw  = (lin & 7) * 32 + (lin >> 3);
  const int ct  = sw >> 7;
  const int r   = sw & 127;
  const int n   = blockIdx.z;
  const int c0  = ct * PXT;
  const int co_base = (wv & 1) * 64;
  const int px_base = (wv >> 1) * 32;
  const int rlo  = min(max(r - 2, 0), IMH - ROWS);
  const int q    = lane >> 4;
  const int p    = lane & 15;
  const int sp  = tid & 3;
  const int scg = (tid >> 2) & 63;
  const int srr = tid >> 8;

  const float* xn = x + (size_t)n * CIN * NPIX;

  floatx4 nx[4];
  #pragma unroll
  for (int c = 0; c < 2; c++)
    #pragma unroll
    for (int rw = 0; rw < 2; rw++)
      nx[c * 2 + rw] = *(const floatx4*)(xn + (size_t)(sp * 2 + c) * NPIX
                                         + (size_t)(rlo + srr * 2 + rw) * IMW + scg * 4);

  {
    int myk = -1;
    if (lane == 0) myk = wv;
    if (wv == 0 && lane == 32) myk = 8;
    if (myk >= 0) {
      const double pi = 3.14159265358979323846;
      double dphi = pi / IMH;
      double dth  = 2.0 * pi / IMW;
      double t  = tan(dth);
      double pp = tan(dphi);
      double sp_ = pp / cos(dth);
      double phi  = -(((double)r + 0.5) / IMH * pi - pi * 0.5);
      double sphi = sin(phi), cphi = cos(phi);
      int i = myk / 3, j = myk % 3;
      double atv, new_r;
      if (myk == 4) {
        atv = 0.0; new_r = (double)r;
      } else {
        double X = (j == 0) ? -t : ((j == 2) ? t : 0.0);
        double Y = 0.0;
        if (i == 0)      Y = (j == 1) ?  pp :  sp_;
        else if (i == 2) Y = (j == 1) ? -pp : -sp_;
        double rho = sqrt(X * X + Y * Y);
        double v   = atan(rho);
        double sv = sin(v), cv = cos(v);
        double arg = cv * sphi + Y * sv * cphi / rho;
        arg = fmin(1.0, fmax(-1.0, arg));
        double new_phi = asin(arg);
        double denom = rho * cphi * cv - Y * sphi * sv;
        atv = atan(X * sv / denom);
        new_r = (-new_phi + pi * 0.5) * IMH / pi - 0.5;
      }
      float gy = (float)(new_r * 2.0 / IMH - 1.0);
      float iy = ((gy + 1.0f) * (float)IMH - 1.0f) * 0.5f;
      float fy = floorf(iy); int y0 = (int)fy;
      float wy1 = iy - fy, wy0 = 1.0f - wy1;
      int y1 = y0 + 1;
      bool vy0 = (y0 >= 0) & (y0 <= IMH - 1);
      bool vy1 = (y1 >= 0) & (y1 <= IMH - 1);
      int y0c = min(max(y0, 0), IMH - 1), y1c = min(max(y1, 0), IMH - 1);
      int rt = min(max(y0c - rlo, 0), ROWS - 1);
      int rb = min(max(y1c - rlo, 0), ROWS - 1);
      tapA[myk] = atv;
      tapWy[myk][0] = vy0 ? wy0 : 0.0f;
      tapWy[myk][1] = vy1 ? wy1 : 0.0f;
      tapRo[myk][0] = rt * F_RSTW;
      tapRo[myk][1] = rb * F_RSTW;
    }
  }
  __syncthreads();

  {
    const double pi = 3.14159265358979323846;
    #pragma unroll
    for (int dd = 0; dd < 3; dd++) {
      if (dd < 2 || tid < NDPB - 1024) {
        int d  = tid + dd * 512;
        int px = d & (PXT - 1), k = d >> 7;
        int c  = c0 + px;
        double nc;
        if (k == 4) {
          nc = (double)c;
        } else {
          double theta = ((double)c + 0.5) / IMW * (2.0 * pi) - pi;
          double new_theta = theta + tapA[k];
          nc = (new_theta + pi) * IMW / (2.0 * pi) - 0.5;
          nc = fmod(nc + (double)IMW, (double)IMW);
        }
        float gx = (float)(nc * 2.0 / IMW - 1.0);
        float ix = ((gx + 1.0f) * (float)IMW - 1.0f) * 0.5f;
        float fx = floorf(ix); int x0 = (int)fx;
        float wx1 = ix - fx, wx0 = 1.0f - wx1;
        int x1 = x0 + 1;
        int x0c = max(x0, 0);
        float w_lo = (x0 >= 0) ? wx0 : wx1;
        float w_hi = (x0 >= 0) ? ((x1 <= IMW - 1) ? wx1 : 0.0f) : 0.0f;
        float wy0m = tapWy[k][0], wy1m = tapWy[k][1];
        int sh0 = ((x0c >> 4) & 1) * 2;
        int sh1 = (((x0c + 1) >> 4) & 1) * 2;
        int dc  = F_CSTW + sh1 - sh0;
        int offt = tapRo[k][0] + x0c * F_CSTW + sh0;
        int offb = tapRo[k][1] + x0c * F_CSTW + sh0;
        uintx4 rec;
        rec.x = (unsigned)(offt | (offb << 16));
        rec.y = pkrtz2(wy0m * w_lo, wy0m * w_hi);
        rec.z = pkrtz2(wy1m * w_lo, wy1m * w_hi);
        rec.w = (unsigned)dc;
        *(uintx4*)&descL[(k * PXT + px) * 4] = rec;
      }
    }
  }
  if (tid < 3 * PXT) {
    uintx4 zr = {0u, 0u, 0u, (unsigned)F_CSTW};
    *(uintx4*)&descL[((9 + (tid >> 7)) * PXT + (tid & (PXT - 1))) * 4] = zr;
  }

  #pragma unroll
  for (int rw = 0; rw < 2; rw++)
    #pragma unroll
    for (int i = 0; i < 4; i++) {
      int col = scg * 4 + i;
      int sh = ((col >> 4) & 1) * 2;
      stg[0][(srr * 2 + rw) * F_RSTW + col * F_CSTW + sh + sp] =
          pkrtz2(nx[rw][i], nx[2 + rw][i]);
    }
  if (tid < 32) stg[tid >> 4][((tid >> 2) & 3) * F_RSTW + 256 * F_CSTW + (tid & 3)] = 0u;

  floatx4 acc[4][2];
  #pragma unroll
  for (int mt = 0; mt < 4; mt++)
    #pragma unroll
    for (int nt = 0; nt < 2; nt++)
      acc[mt][nt] = (floatx4){0.f, 0.f, 0.f, 0.f};

  __syncthreads();

  #pragma unroll 1
  for (int cb = 0; cb < 8; cb++) {
    if (cb < 7) {
      #pragma unroll
      for (int c = 0; c < 2; c++)
        #pragma unroll
        for (int rw = 0; rw < 2; rw++)
          nx[c * 2 + rw] = *(const floatx4*)(xn + (size_t)((cb + 1) * 8 + sp * 2 + c) * NPIX
                                             + (size_t)(rlo + srr * 2 + rw) * IMW + scg * 4);
    }
    const unsigned int* sb = &stg[cb & 1][0];
    #pragma unroll
    for (int nt = 0; nt < 2; nt++) {
      const int pxl = px_base + nt * 16 + p;
      #pragma unroll
      for (int ks = 0; ks < 3; ks++) {
        uintx4 rec = *(const uintx4*)&descL[((ks * 4 + q) * PXT + pxl) * 4];
        unsigned op = rec.x;
        int dc = (int)rec.w;
        const unsigned int* pt = sb + (op & 0xFFFFu);
        const unsigned int* pb = sb + (op >> 16);
        half4 t0  = *(const half4*)(pt);
        half4 t0h = *(const half4*)(pt + 2);
        half4 t1  = *(const half4*)(pt + dc);
        half4 t1h = *(const half4*)(pt + dc + 2);
        half4 b0  = *(const half4*)(pb);
        half4 b0h = *(const half4*)(pb + 2);
        half4 b1  = *(const half4*)(pb + dc);
        half4 b1h = *(const half4*)(pb + dc + 2);
        half4 W0 = bcl(rec.y), W1 = bch(rec.y);
        half4 W2 = bcl(rec.z), W3 = bch(rec.z);
        half4 slo = t0 * W0 + t1 * W1 + b0 * W2 + b1 * W3;
        half4 shi = t0h * W0 + t1h * W1 + b0h * W2 + b1h * W3;
        half8 b = __builtin_shufflevector(slo, shi, 0, 1, 2, 3, 4, 5, 6, 7);
        const unsigned short* arow =
            wbf + (size_t)((cb * 12 + ks * 4 + q) * COUT + co_base + p) * 8;
        __builtin_amdgcn_s_setprio(1);
        #pragma unroll
        for (int mt = 0; mt < 4; mt++) {
          half8 a = *(const half8*)(arow + mt * 16 * 8);
          acc[mt][nt] = __builtin_amdgcn_mfma_f32_16x16x32_f16(a, b, acc[mt][nt], 0, 0, 0);
        }
        __builtin_amdgcn_s_setprio(0);
      }
    }
    if (cb < 7) {
      #pragma unroll
      for (int rw = 0; rw < 2; rw++)
        #pragma unroll
        for (int i = 0; i < 4; i++) {
          int col = scg * 4 + i;
          int sh = ((col >> 4) & 1) * 2;
          stg[(cb + 1) & 1][(srr * 2 + rw) * F_RSTW + col * F_CSTW + sh + sp] =
              pkrtz2(nx[rw][i], nx[2 + rw][i]);
        }
    }
    __syncthreads();
  }

  #pragma unroll
  for (int mt = 0; mt < 4; mt++)
    #pragma unroll
    for (int nt = 0; nt < 2; nt++)
      #pragma unroll
      for (int rg = 0; rg < 4; rg++) {
        const int co = co_base + mt * 16 + q * 4 + rg;
        const int cc = c0 + px_base + nt * 16 + p;
        out[(((size_t)n * COUT + co) * IMH + r) * IMW + cc] = acc[mt][nt][rg] + bias[co];
      }
}

extern "C" void kernel_launch(void* const* d_in, const int* in_sizes, int n_in,
                              void* d_out, int out_size, void* d_ws, size_t ws_size,
                              hipStream_t stream) {
  const float* x    = (const float*)d_in[0];
  const float* w    = (const float*)d_in[1];
  const float* bias = (const float*)d_in[2];
  float* out = (float*)d_out;
  unsigned short* wbf = (unsigned short*)d_ws;
  (void)in_sizes; (void)n_in; (void)out_size;

  hipLaunchKernelGGL(prep_w_kernel, dim3((COUT * 8 * KCH + 255) / 256), dim3(256), 0, stream, w, wbf);
  if (ws_size >= (size_t)XT_OFF + XT_BYTES) {
    unsigned short* xt = (unsigned short*)((char*)d_ws + XT_OFF);
    hipLaunchKernelGGL(prep_x_kernel, dim3((NB * 8 * IMH * IMW) / 256), dim3(256), 0, stream, x, xt);
    hipLaunchKernelGGL(sphconv_fast, dim3(IMW / PXT, IMH, NB), dim3(512), 0, stream,
                       xt, wbf, bias, out);
  } else {
    hipLaunchKernelGGL(sphconv_fb, dim3(IMW / PXT, IMH, NB), dim3(512), 0, stream,
                       x, wbf, bias, out);
  }
}